// Round 13
// baseline (820.001 us; speedup 1.0000x reference)
//
#include <hip/hip_runtime.h>
#include <hip/hip_bf16.h>
#include <stdint.h>

#define DIM 256
#define HEADS 8
#define INNER 512
#define NPTS 32768
#define MTOT (4 * NPTS)   // 131072 rows total
#define PADN 136   // wsmT/fxS row pad in shorts (16B-aligned rows)
#define PADD 72    // xm row pad in shorts

typedef unsigned int uint32;
typedef short bf16x8 __attribute__((ext_vector_type(8)));
typedef float f32x4 __attribute__((ext_vector_type(4)));
typedef uint32 u32x4 __attribute__((ext_vector_type(4)));

static __device__ __forceinline__ unsigned short f2bf(float f) {
    unsigned int u = __float_as_uint(f);
    u += 0x7fffu + ((u >> 16) & 1u);   // RNE
    return (unsigned short)(u >> 16);
}
static __device__ __forceinline__ float bf2f(unsigned short v) {
    return __uint_as_float(((unsigned int)v) << 16);
}
static __device__ __forceinline__ uint32 pkbf(float a, float b) {
    __hip_bfloat162 h = __float22bfloat162_rn(make_float2(a, b));
    return *(reinterpret_cast<uint32*>(&h));
}
static __device__ __forceinline__ void gll16(const void* g, const void* l) {
    __builtin_amdgcn_global_load_lds(
        (const __attribute__((address_space(1))) uint32*)g,
        (__attribute__((address_space(3))) uint32*)l, 16, 0, 0);
}

// ---------------------------------------------------------------------------
// K0: prep — Wfx|Wx -> combined transposed bf16 [1024][256]; Wsl -> [g][d];
// blocks >=5: x fp32 -> bf16 (RNE), so K1 stages A via global_load_lds.
// ---------------------------------------------------------------------------
__global__ __launch_bounds__(256) void k_prep(
    const float* __restrict__ Wfx, const float* __restrict__ Wx,
    const float* __restrict__ Wsl, const float* __restrict__ x,
    unsigned short* __restrict__ Wbt, unsigned short* __restrict__ WslT,
    unsigned short* __restrict__ xb)
{
    const int blk = blockIdx.x, t = threadIdx.x;
    if (blk < 4) {
        const int n = blk * 256 + t;
        for (int k8 = 0; k8 < 256; k8 += 8) {
            unsigned short v[8];
#pragma unroll
            for (int j = 0; j < 8; j++) {
                float f = (n < 512) ? Wfx[(size_t)(k8 + j) * 512 + n]
                                    : Wx[(size_t)(k8 + j) * 512 + (n - 512)];
                v[j] = f2bf(f);
            }
            ushort4 u0 = {v[0], v[1], v[2], v[3]};
            ushort4 u1 = {v[4], v[5], v[6], v[7]};
            *(ushort4*)(Wbt + (size_t)n * 256 + k8) = u0;
            *(ushort4*)(Wbt + (size_t)n * 256 + k8 + 4) = u1;
        }
    } else if (blk == 4) {
        const int g = t >> 2, d0 = (t & 3) * 16;
        unsigned short v[16];
#pragma unroll
        for (int i = 0; i < 16; i++) v[i] = f2bf(Wsl[(size_t)(d0 + i) * 64 + g]);
#pragma unroll
        for (int q = 0; q < 4; q++) {
            ushort4 u = {v[q * 4], v[q * 4 + 1], v[q * 4 + 2], v[q * 4 + 3]};
            *(ushort4*)(WslT + (size_t)g * 64 + d0 + q * 4) = u;
        }
    } else {
        // x [4*32768][256] fp32 -> bf16, grid-stride, 8 elems/thread/iter
        const size_t TOT = (size_t)MTOT * 256;
        size_t i = ((size_t)(blk - 5) * 256 + t) * 8;
        const size_t stride = (size_t)(gridDim.x - 5) * 256 * 8;
        for (; i < TOT; i += stride) {
            float4 f0 = *(const float4*)(x + i);
            float4 f1 = *(const float4*)(x + i + 4);
            u32x4 v;
            v.x = pkbf(f0.x, f0.y); v.y = pkbf(f0.z, f0.w);
            v.z = pkbf(f1.x, f1.y); v.w = pkbf(f1.z, f1.w);
            *(u32x4*)(xb + i) = v;
        }
    }
}

// ---------------------------------------------------------------------------
// K1: mega-fused per-head kernel (1-D grid 2048, XCD-affinity swizzle).
// R10-exact (proven 353us): 51KB LDS, (256,3), compile-time gather indices.
// ---------------------------------------------------------------------------
__global__ __launch_bounds__(256, 3) void k_projfused(
    const unsigned short* __restrict__ xb,     // [M][256] bf16
    const unsigned short* __restrict__ Wbt,    // [1024][256] bf16
    const float* __restrict__ bfx, const float* __restrict__ bx,
    const unsigned short* __restrict__ WslTg,  // [64 g][64 d] bf16
    const float* __restrict__ bsl, const float* __restrict__ temp,
    unsigned short* __restrict__ wN,           // [8 h][M][64 g] bf16 planes
    float* __restrict__ tp,                    // [b][h][64 cb][64 g][64 d] partials
    float* __restrict__ np)                    // [b][h][64 cb][4 w][64 g] partials
{
    __shared__ unsigned short S[128 * 64 * 2];   // A[128][64] + B[128][64]; fxS overlay
    __shared__ unsigned short X[128 * PADD];     // xm; wsmT overlay

    // XCD-affinity decode: blocks L with L%8==xcd serve chunks [xcd*32, xcd*32+32)
    const int L = blockIdx.x;
    const int xcd = L & 7;
    const int j = L >> 3;                  // 0..255
    const int chunk = xcd * 32 + (j >> 3); // 0..255
    const int h = j & 7;

    const int b = chunk >> 6;              // 64 chunks per batch
    const int t = threadIdx.x;
    const int w = t >> 6, lane = t & 63;
    const int wm = w >> 1, wn = w & 1;
    const int l15 = lane & 15, quad = lane >> 4;

    unsigned short* A  = S;                // [128][64]
    unsigned short* Bs = S + 128 * 64;     // [128][64]
    unsigned short* fxS = S;               // [64][PADN] overlay
    unsigned short* wsmT = X;              // [64][PADN] overlay

    bf16x8 wslf[4][2];
#pragma unroll
    for (int c = 0; c < 4; c++)
#pragma unroll
        for (int ks = 0; ks < 2; ks++)
            wslf[c][ks] = *(const bf16x8*)&WslTg[(c * 16 + l15) * 64 + ks * 32 + quad * 8];

    float tv = temp[h];
    tv = fminf(fmaxf(tv, 0.1f), 5.0f);
    const float itemp = 1.0f / tv;
    float bsl_c[4], bfx_c[4], bx_c[4];
#pragma unroll
    for (int c = 0; c < 4; c++) {
        bsl_c[c] = bsl[c * 16 + l15];
        bfx_c[c] = bfx[h * 64 + c * 16 + l15];
        bx_c[c]  = bx[h * 64 + c * 16 + l15];
    }

    f32x4 pacc[4];
#pragma unroll
    for (int c = 0; c < 4; c++) pacc[c] = (f32x4){0.f, 0.f, 0.f, 0.f};
    float ns[4] = {0.f, 0.f, 0.f, 0.f};

    unsigned short* plane = wN + (size_t)h * MTOT * 64;

    for (int mt = 0; mt < 4; mt++) {
        const int n_in_b = ((chunk & 63) * 4 + mt) * 128;
        const size_t m0 = (size_t)b * NPTS + n_in_b;

        f32x4 acc[4][4];
#pragma unroll
        for (int r = 0; r < 4; r++)
#pragma unroll
            for (int c = 0; c < 4; c++) acc[r][c] = (f32x4){0.f, 0.f, 0.f, 0.f};

        for (int kb = 0; kb < 256; kb += 64) {
            __syncthreads();
#pragma unroll
            for (int rr = 0; rr < 4; rr++) {
                int flat = rr * 256 + t;
                int row = flat >> 3, colg = (flat & 7) * 8;
                gll16(xb + (m0 + row) * 256 + kb + colg, (char*)A + flat * 16);
                int grow = (rr < 2) ? (h * 64 + row) : (512 + h * 64 + (row - 64));
                gll16(Wbt + (size_t)grow * 256 + kb + colg, (char*)Bs + flat * 16);
            }
            __syncthreads();
#pragma unroll
            for (int ks = 0; ks < 2; ks++) {
                bf16x8 af[4], bfv[4];
#pragma unroll
                for (int r = 0; r < 4; r++)
                    af[r] = *(const bf16x8*)&A[(wm * 64 + r * 16 + l15) * 64 + ks * 32 + quad * 8];
#pragma unroll
                for (int c = 0; c < 4; c++)
                    bfv[c] = *(const bf16x8*)&Bs[(wn * 64 + c * 16 + l15) * 64 + ks * 32 + quad * 8];
#pragma unroll
                for (int r = 0; r < 4; r++)
#pragma unroll
                    for (int c = 0; c < 4; c++)
                        acc[r][c] = __builtin_amdgcn_mfma_f32_16x16x32_bf16(af[r], bfv[c], acc[r][c], 0, 0, 0);
            }
        }

        // ---- epilogue: fx -> fxS (wn==0 waves), x_mid -> xm (wn==1 waves) ----
        __syncthreads();
        if (wn == 0) {
#pragma unroll
            for (int r = 0; r < 4; r++)
#pragma unroll
                for (int c = 0; c < 4; c++) {
                    ushort4 u;
                    u.x = f2bf(acc[r][c][0] + bfx_c[c]);
                    u.y = f2bf(acc[r][c][1] + bfx_c[c]);
                    u.z = f2bf(acc[r][c][2] + bfx_c[c]);
                    u.w = f2bf(acc[r][c][3] + bfx_c[c]);
                    *(ushort4*)&fxS[(c * 16 + l15) * PADN + wm * 64 + r * 16 + quad * 4] = u;
                }
        } else {
#pragma unroll
            for (int r = 0; r < 4; r++)
#pragma unroll
                for (int c = 0; c < 4; c++)
#pragma unroll
                    for (int j2 = 0; j2 < 4; j2++)
                        X[(wm * 64 + r * 16 + quad * 4 + j2) * PADD + c * 16 + l15] =
                            f2bf(acc[r][c][j2] + bx_c[c]);
        }
        __syncthreads();

        // ---- logits MFMA ----
        f32x4 lacc[2][4];
#pragma unroll
        for (int rt = 0; rt < 2; rt++)
#pragma unroll
            for (int c = 0; c < 4; c++)
                lacc[rt][c] = (f32x4){bsl_c[c], bsl_c[c], bsl_c[c], bsl_c[c]};
#pragma unroll
        for (int ks = 0; ks < 2; ks++) {
            bf16x8 laf[2];
#pragma unroll
            for (int rt = 0; rt < 2; rt++)
                laf[rt] = *(const bf16x8*)&X[(w * 32 + rt * 16 + l15) * PADD + ks * 32 + quad * 8];
#pragma unroll
            for (int rt = 0; rt < 2; rt++)
#pragma unroll
                for (int c = 0; c < 4; c++)
                    lacc[rt][c] = __builtin_amdgcn_mfma_f32_16x16x32_bf16(laf[rt], wslf[c][ks], lacc[rt][c], 0, 0, 0);
        }
        __syncthreads();   // xm dead -> wsmT overlays X

        // ---- softmax -> wsmT[g][n]; ns ----
#pragma unroll
        for (int rt = 0; rt < 2; rt++) {
            float wv[4][4];
#pragma unroll
            for (int j2 = 0; j2 < 4; j2++) {
                float v0 = lacc[rt][0][j2] * itemp;
                float v1 = lacc[rt][1][j2] * itemp;
                float v2 = lacc[rt][2][j2] * itemp;
                float v3 = lacc[rt][3][j2] * itemp;
                float mx = fmaxf(fmaxf(v0, v1), fmaxf(v2, v3));
                mx = fmaxf(mx, __shfl_xor(mx, 1));
                mx = fmaxf(mx, __shfl_xor(mx, 2));
                mx = fmaxf(mx, __shfl_xor(mx, 4));
                mx = fmaxf(mx, __shfl_xor(mx, 8));
                float e0 = __expf(v0 - mx), e1 = __expf(v1 - mx);
                float e2 = __expf(v2 - mx), e3 = __expf(v3 - mx);
                float s = e0 + e1 + e2 + e3;
                s += __shfl_xor(s, 1);
                s += __shfl_xor(s, 2);
                s += __shfl_xor(s, 4);
                s += __shfl_xor(s, 8);
                float inv = 1.0f / s;
                wv[0][j2] = e0 * inv; wv[1][j2] = e1 * inv;
                wv[2][j2] = e2 * inv; wv[3][j2] = e3 * inv;
                ns[0] += wv[0][j2]; ns[1] += wv[1][j2];
                ns[2] += wv[2][j2]; ns[3] += wv[3][j2];
            }
#pragma unroll
            for (int c = 0; c < 4; c++) {
                ushort4 u;
                u.x = f2bf(wv[c][0]); u.y = f2bf(wv[c][1]);
                u.z = f2bf(wv[c][2]); u.w = f2bf(wv[c][3]);
                *(ushort4*)&wsmT[(c * 16 + l15) * PADN + w * 32 + rt * 16 + quad * 4] = u;
            }
        }
        __syncthreads();

        // ---- pooling MFMA ----
#pragma unroll
        for (int kk = 0; kk < 4; kk++) {
            bf16x8 paf = *(const bf16x8*)&wsmT[(w * 16 + l15) * PADN + kk * 32 + quad * 8];
#pragma unroll
            for (int c = 0; c < 4; c++) {
                bf16x8 pbf = *(const bf16x8*)&fxS[(c * 16 + l15) * PADN + kk * 32 + quad * 8];
                pacc[c] = __builtin_amdgcn_mfma_f32_16x16x32_bf16(paf, pbf, pacc[c], 0, 0, 0);
            }
        }

        // ---- wN write: per-head plane [M][64]; a wave stores 8 consecutive
        //      rows x 128 B = 1 KB fully contiguous per instruction ----
        {
            const int rsub = t >> 3;          // 0..31
            const int c16 = (t & 7) * 8;      // 16-B g-chunk
#pragma unroll
            for (int rr = 0; rr < 4; rr++) {
                const int n = rr * 32 + rsub;
                __attribute__((aligned(16))) unsigned short tmp[8];
#pragma unroll
                for (int i = 0; i < 8; i++)
                    tmp[i] = wsmT[(c16 + i) * PADN + n];
                *(u32x4*)(plane + (m0 + n) * 64 + c16) = *(const u32x4*)tmp;
            }
        }
    }

    // ---- block-end partial writes (plain stores, no atomics) ----
    const size_t cb = (size_t)(b * 8 + h) * 64 + (chunk & 63);
    float* tpb = tp + cb * 4096;
#pragma unroll
    for (int c = 0; c < 4; c++)
#pragma unroll
        for (int j2 = 0; j2 < 4; j2++)
            tpb[(size_t)(w * 16 + quad * 4 + j2) * 64 + c * 16 + l15] = pacc[c][j2];
#pragma unroll
    for (int c = 0; c < 4; c++) {
        ns[c] += __shfl_xor(ns[c], 16);
        ns[c] += __shfl_xor(ns[c], 32);
    }
    if (quad == 0) {
        float* npb = np + (cb * 4 + w) * 64;
#pragma unroll
        for (int c = 0; c < 4; c++)
            npb[c * 16 + l15] = ns[c];
    }
}

// ---------------------------------------------------------------------------
// K2: reduce per-chunk partials -> token_num [bh][64][64], norm [bh][64].
// ---------------------------------------------------------------------------
__global__ __launch_bounds__(256) void k_red(
    const float* __restrict__ tp, const float* __restrict__ np,
    float* __restrict__ token_num, float* __restrict__ norm)
{
    const int bh = blockIdx.x >> 4, seg = blockIdx.x & 15;
    const int t = threadIdx.x;
    float s = 0.f;
    const float* base = tp + (size_t)bh * 64 * 4096 + seg * 256 + t;
    for (int c = 0; c < 64; c++) s += base[(size_t)c * 4096];
    token_num[(size_t)bh * 4096 + seg * 256 + t] = s;
    if (seg == 0 && t < 64) {
        float nsum = 0.f;
        const float* nb = np + (size_t)bh * 64 * 4 * 64 + t;
        for (int i = 0; i < 256; i++) nsum += nb[(size_t)i * 64];
        norm[bh * 64 + t] = nsum;
    }
}

// ---------------------------------------------------------------------------
// K3: tiny attention over 64 slice tokens per (b,h). (unchanged; proven)
// ---------------------------------------------------------------------------
__global__ __launch_bounds__(256) void k_attn(
    const float* __restrict__ token_num, const float* __restrict__ norm,
    const float* __restrict__ Wq, const float* __restrict__ Wk,
    const float* __restrict__ Wv, float* __restrict__ out_slice)
{
    const int bh = blockIdx.x;
    const int t = threadIdx.x;
    const int gg = t >> 2, qq = t & 3;

    __shared__ float tok[64][68];
    __shared__ float qS[64][68];
    __shared__ float kS[64][68];
    __shared__ float vS[64][68];
    __shared__ float pS[64][68];
    __shared__ float Wqs[64][64], Wks[64][64], Wvs[64][64];

    for (int i = t; i < 4096; i += 256) {
        int g = i >> 6, dd = i & 63;
        Wqs[g][dd] = Wq[i];
        Wks[g][dd] = Wk[i];
        Wvs[g][dd] = Wv[i];
        tok[g][dd] = token_num[(size_t)bh * 4096 + i] / (norm[bh * 64 + g] + 1e-5f);
    }
    __syncthreads();

    float aq[16] = {}, ak[16] = {}, av[16] = {};
    for (int k = 0; k < 64; k++) {
        const float tv = tok[gg][k];
        const float4* wq4 = (const float4*)&Wqs[k][qq * 16];
        const float4* wk4 = (const float4*)&Wks[k][qq * 16];
        const float4* wv4 = (const float4*)&Wvs[k][qq * 16];
#pragma unroll
        for (int j4 = 0; j4 < 4; j4++) {
            float4 a = wq4[j4], bq = wk4[j4], c = wv4[j4];
            aq[j4*4+0] = fmaf(tv, a.x,  aq[j4*4+0]);
            aq[j4*4+1] = fmaf(tv, a.y,  aq[j4*4+1]);
            aq[j4*4+2] = fmaf(tv, a.z,  aq[j4*4+2]);
            aq[j4*4+3] = fmaf(tv, a.w,  aq[j4*4+3]);
            ak[j4*4+0] = fmaf(tv, bq.x, ak[j4*4+0]);
            ak[j4*4+1] = fmaf(tv, bq.y, ak[j4*4+1]);
            ak[j4*4+2] = fmaf(tv, bq.z, ak[j4*4+2]);
            ak[j4*4+3] = fmaf(tv, bq.w, ak[j4*4+3]);
            av[j4*4+0] = fmaf(tv, c.x,  av[j4*4+0]);
            av[j4*4+1] = fmaf(tv, c.y,  av[j4*4+1]);
            av[j4*4+2] = fmaf(tv, c.z,  av[j4*4+2]);
            av[j4*4+3] = fmaf(tv, c.w,  av[j4*4+3]);
        }
    }
#pragma unroll
    for (int j = 0; j < 16; j++) {
        qS[gg][qq * 16 + j] = aq[j];
        kS[gg][qq * 16 + j] = ak[j];
        vS[gg][qq * 16 + j] = av[j];
    }
    __syncthreads();

    float sc[16] = {};
    for (int d4 = 0; d4 < 16; d4++) {
        float4 q4 = *(const float4*)&qS[gg][d4 * 4];
#pragma unroll
        for (int j = 0; j < 16; j++) {
            float4 k4 = *(const float4*)&kS[qq * 16 + j][d4 * 4];
            sc[j] = fmaf(q4.x, k4.x, sc[j]);
            sc[j] = fmaf(q4.y, k4.y, sc[j]);
            sc[j] = fmaf(q4.z, k4.z, sc[j]);
            sc[j] = fmaf(q4.w, k4.w, sc[j]);
        }
    }
    const float SCALE = 0.125f;
    float mx = -1e30f;
#pragma unroll
    for (int j = 0; j < 16; j++) { sc[j] *= SCALE; mx = fmaxf(mx, sc[j]); }
    mx = fmaxf(mx, __shfl_xor(mx, 1));
    mx = fmaxf(mx, __shfl_xor(mx, 2));
    float s = 0.f;
#pragma unroll
    for (int j = 0; j < 16; j++) { sc[j] = __expf(sc[j] - mx); s += sc[j]; }
    s += __shfl_xor(s, 1);
    s += __shfl_xor(s, 2);
    const float invs = 1.0f / s;
#pragma unroll
    for (int j = 0; j < 16; j++) pS[gg][qq * 16 + j] = sc[j] * invs;
    __syncthreads();

    float oo[16] = {};
    for (int j = 0; j < 64; j++) {
        const float pv = pS[gg][j];
        const float4* v4p = (const float4*)&vS[j][qq * 16];
#pragma unroll
        for (int d4 = 0; d4 < 4; d4++) {
            float4 v4 = v4p[d4];
            oo[d4*4+0] = fmaf(pv, v4.x, oo[d4*4+0]);
            oo[d4*4+1] = fmaf(pv, v4.y, oo[d4*4+1]);
            oo[d4*4+2] = fmaf(pv, v4.z, oo[d4*4+2]);
            oo[d4*4+3] = fmaf(pv, v4.w, oo[d4*4+3]);
        }
    }
    float* op = out_slice + (size_t)bh * 4096 + gg * 64 + qq * 16;
#pragma unroll
    for (int d4 = 0; d4 < 4; d4++) {
        float4 o; o.x = oo[d4*4+0]; o.y = oo[d4*4+1]; o.z = oo[d4*4+2]; o.w = oo[d4*4+3];
        *(float4*)(op + d4 * 4) = o;
    }
}

// ---------------------------------------------------------------------------
// K5: Mt[c][hg] = sum_d os[b][h][g][d] * W_out[h*64+d][c], split hi/lo bf16
// ---------------------------------------------------------------------------
__global__ __launch_bounds__(256) void k_m(
    const float* __restrict__ os, const float* __restrict__ W_out,
    unsigned short* __restrict__ Mt_hi, unsigned short* __restrict__ Mt_lo)
{
    const int h = blockIdx.x, b = blockIdx.y;
    const int t = threadIdx.x;   // c
    __shared__ float osl[64][65];
    for (int i = t; i < 4096; i += 256)
        osl[i >> 6][i & 63] = os[(size_t)(b * 8 + h) * 4096 + i];
    __syncthreads();
    float acc[64];
#pragma unroll
    for (int g = 0; g < 64; g++) acc[g] = 0.f;
    for (int d = 0; d < 64; d++) {
        float wv = W_out[(size_t)(h * 64 + d) * 256 + t];
#pragma unroll
        for (int g = 0; g < 64; g++) acc[g] = fmaf(osl[g][d], wv, acc[g]);
    }
    unsigned short* ph = Mt_hi + (size_t)(b * 256 + t) * 512 + h * 64;
    unsigned short* pl = Mt_lo + (size_t)(b * 256 + t) * 512 + h * 64;
#pragma unroll
    for (int g4 = 0; g4 < 16; g4++) {
        ushort4 uh, ul;
        unsigned short hh; float v, lo;
        v = acc[g4*4+0]; hh = f2bf(v); lo = v - bf2f(hh); uh.x = hh; ul.x = f2bf(lo);
        v = acc[g4*4+1]; hh = f2bf(v); lo = v - bf2f(hh); uh.y = hh; ul.y = f2bf(lo);
        v = acc[g4*4+2]; hh = f2bf(v); lo = v - bf2f(hh); uh.z = hh; ul.z = f2bf(lo);
        v = acc[g4*4+3]; hh = f2bf(v); lo = v - bf2f(hh); uh.w = hh; ul.w = f2bf(lo);
        *(ushort4*)(ph + g4 * 4) = uh;
        *(ushort4*)(pl + g4 * 4) = ul;
    }
}

// ---------------------------------------------------------------------------
// K6: out = wN @ (Mt_hi+Mt_lo)^T + bout.  R11: BM=128 x BN=256 (full-N),
// 512 threads / 8 waves (2 M-groups x 4 N-groups of 64x64 wave-tiles).
// Mechanism: 64 MFMAs per wave between barriers (2x amortization of the
// wN staging drain) and wN rows read ONCE (ntile duplication removed,
// -134 MB reads). LDS 80 KB -> 2 blocks/CU = 16 waves/CU.
// (512,2) NOT (512,4): 4 waves/EU forcing caused the R7 spill disaster.
// ---------------------------------------------------------------------------
__global__ __launch_bounds__(512, 2) void k_out(
    const unsigned short* __restrict__ wN,
    const unsigned short* __restrict__ Mt_hi, const unsigned short* __restrict__ Mt_lo,
    const float* __restrict__ bout, float* __restrict__ out)
{
    __shared__ unsigned short A[128 * 64];    // 16 KB
    __shared__ unsigned short Bh[256 * 64];   // 32 KB
    __shared__ unsigned short Bl[256 * 64];   // 32 KB
    const int L = blockIdx.x;              // 0..1023
    const int m0 = L * 128;
    const int b = m0 >> 15;
    const int t = threadIdx.x;             // 0..511
    const int w = t >> 6, lane = t & 63, l15 = lane & 15, quad = lane >> 4;
    const int wm = w >> 2, wn = w & 3;     // 2 x 4 wave grid

    f32x4 acc[4][4];
#pragma unroll
    for (int r = 0; r < 4; r++)
#pragma unroll
        for (int c = 0; c < 4; c++) acc[r][c] = (f32x4){0.f, 0.f, 0.f, 0.f};

    for (int kb = 0; kb < 512; kb += 64) {
        const unsigned short* planeA = wN + (size_t)(kb >> 6) * MTOT * 64;
        __syncthreads();
        // A: 128x64 = 1024 16B-slots (2/thread)
#pragma unroll
        for (int rr = 0; rr < 2; rr++) {
            int flat = rr * 512 + t;
            int row = flat >> 3, col = (flat & 7) * 8;
            gll16(planeA + (size_t)(m0 + row) * 64 + col, (char*)A + flat * 16);
        }
        // Bh/Bl: 256x64 = 2048 slots each (4/thread each), L2-resident Mt
#pragma unroll
        for (int rr = 0; rr < 4; rr++) {
            int flat = rr * 512 + t;
            int row = flat >> 3, col = (flat & 7) * 8;
            gll16(Mt_hi + (size_t)(b * 256 + row) * 512 + kb + col, (char*)Bh + flat * 16);
            gll16(Mt_lo + (size_t)(b * 256 + row) * 512 + kb + col, (char*)Bl + flat * 16);
        }
        __syncthreads();
#pragma unroll
        for (int ks = 0; ks < 2; ks++) {
            bf16x8 af[4], bh4[4], bl4[4];
#pragma unroll
            for (int r = 0; r < 4; r++)
                af[r] = *(const bf16x8*)&A[(wm * 64 + r * 16 + l15) * 64 + ks * 32 + quad * 8];
#pragma unroll
            for (int c = 0; c < 4; c++) {
                bh4[c] = *(const bf16x8*)&Bh[(wn * 64 + c * 16 + l15) * 64 + ks * 32 + quad * 8];
                bl4[c] = *(const bf16x8*)&Bl[(wn * 64 + c * 16 + l15) * 64 + ks * 32 + quad * 8];
            }
#pragma unroll
            for (int r = 0; r < 4; r++)
#pragma unroll
                for (int c = 0; c < 4; c++) {
                    acc[r][c] = __builtin_amdgcn_mfma_f32_16x16x32_bf16(af[r], bh4[c], acc[r][c], 0, 0, 0);
                    acc[r][c] = __builtin_amdgcn_mfma_f32_16x16x32_bf16(af[r], bl4[c], acc[r][c], 0, 0, 0);
                }
        }
    }
    float biasc[4];
#pragma unroll
    for (int c = 0; c < 4; c++) biasc[c] = bout[wn * 64 + c * 16 + l15];
#pragma unroll
    for (int r = 0; r < 4; r++)
#pragma unroll
        for (int c = 0; c < 4; c++)
#pragma unroll
            for (int j2 = 0; j2 < 4; j2++)
                out[(size_t)(m0 + wm * 64 + r * 16 + quad * 4 + j2) * 256 + wn * 64 + c * 16 + l15] =
                    acc[r][c][j2] + biasc[c];
}

// ---------------------------------------------------------------------------
extern "C" void kernel_launch(void* const* d_in, const int* in_sizes, int n_in,
                              void* d_out, int out_size, void* d_ws, size_t ws_size,
                              hipStream_t stream) {
    const float* x    = (const float*)d_in[0];
    const float* Wfx  = (const float*)d_in[1];
    const float* bfx  = (const float*)d_in[2];
    const float* Wx   = (const float*)d_in[3];
    const float* bx   = (const float*)d_in[4];
    const float* Wsl  = (const float*)d_in[5];
    const float* bsl  = (const float*)d_in[6];
    const float* temp = (const float*)d_in[7];
    const float* Wq   = (const float*)d_in[8];
    const float* Wk   = (const float*)d_in[9];
    const float* Wv   = (const float*)d_in[10];
    const float* Wout = (const float*)d_in[11];
    const float* bout = (const float*)d_in[12];
    float* out = (float*)d_out;

    const int Mtotal = in_sizes[0] / DIM;   // 131072
    const int B = Mtotal / NPTS;            // 4

    // workspace (~138 MB peak)
    char* p = (char*)d_ws;
    unsigned short* Wbt   = (unsigned short*)p; p += (size_t)1024 * 256 * 2;        // 512 KB
    unsigned short* WslTg = (unsigned short*)p; p += (size_t)64 * 64 * 2;           // 8 KB
    unsigned short* wN    = (unsigned short*)p; p += (size_t)Mtotal * INNER * 2;    // 134 MB
    float* token_num = (float*)p; p += (size_t)B * 8 * 64 * 64 * 4;                 // 512 KB
    float* norm_ws   = (float*)p; p += (size_t)B * 8 * 64 * 4;                      // 8 KB
    float* os_ws     = (float*)p; p += (size_t)B * 8 * 64 * 64 * 4;                 // 512 KB
    unsigned short* Mt_hi = (unsigned short*)p; p += (size_t)B * 256 * 512 * 2;     // 1 MB
    unsigned short* Mt_lo = (unsigned short*)p; p += (size_t)B * 256 * 512 * 2;     // 1 MB

    // d_out (128 MB) double-duty: [0,64MB) xb bf16 x; [64MB,...) partial sums.
    // k_red consumes partials before k_out overwrites out.
    unsigned short* xb = (unsigned short*)d_out;
    float* tp = (float*)((char*)d_out + (size_t)Mtotal * DIM * 2);                  // 33.5 MB
    float* np = tp + (size_t)B * 8 * 64 * 4096;                                     // 2 MB

    k_prep<<<2048, 256, 0, stream>>>(Wfx, Wx, Wsl, x, Wbt, WslTg, xb);
    k_projfused<<<2048, 256, 0, stream>>>(
        xb, Wbt, bfx, bx, WslTg, bsl, temp, wN, tp, np);
    k_red<<<B * 8 * 16, 256, 0, stream>>>(tp, np, token_num, norm_ws);
    k_attn<<<B * 8, 256, 0, stream>>>(token_num, norm_ws, Wq, Wk, Wv, os_ws);
    k_m<<<dim3(8, B), 256, 0, stream>>>(os_ws, Wout, Mt_hi, Mt_lo);
    k_out<<<Mtotal / 128, 512, 0, stream>>>(wN, Mt_hi, Mt_lo, bout, out);
}

// Round 15
// 760.956 us; speedup vs baseline: 1.0776x; 1.0776x over previous
//
#include <hip/hip_runtime.h>
#include <hip/hip_bf16.h>
#include <stdint.h>

#define DIM 256
#define HEADS 8
#define INNER 512
#define NPTS 32768
#define MTOT (4 * NPTS)   // 131072 rows total
#define PADN 136   // wsmT/fxS row pad in shorts (16B-aligned rows)
#define PADD 72    // xm row pad in shorts

typedef unsigned int uint32;
typedef short bf16x8 __attribute__((ext_vector_type(8)));
typedef float f32x4 __attribute__((ext_vector_type(4)));
typedef uint32 u32x4 __attribute__((ext_vector_type(4)));

static __device__ __forceinline__ unsigned short f2bf(float f) {
    unsigned int u = __float_as_uint(f);
    u += 0x7fffu + ((u >> 16) & 1u);   // RNE
    return (unsigned short)(u >> 16);
}
static __device__ __forceinline__ float bf2f(unsigned short v) {
    return __uint_as_float(((unsigned int)v) << 16);
}
static __device__ __forceinline__ uint32 pkbf(float a, float b) {
    __hip_bfloat162 h = __float22bfloat162_rn(make_float2(a, b));
    return *(reinterpret_cast<uint32*>(&h));
}
static __device__ __forceinline__ void gll16(const void* g, const void* l) {
    __builtin_amdgcn_global_load_lds(
        (const __attribute__((address_space(1))) uint32*)g,
        (__attribute__((address_space(3))) uint32*)l, 16, 0, 0);
}

// ---------------------------------------------------------------------------
// K0: prep — Wfx|Wx -> combined transposed bf16 [1024][256]; Wsl -> [g][d];
// blocks >=5: x fp32 -> bf16 (RNE), so K1 stages A via global_load_lds.
// ---------------------------------------------------------------------------
__global__ __launch_bounds__(256) void k_prep(
    const float* __restrict__ Wfx, const float* __restrict__ Wx,
    const float* __restrict__ Wsl, const float* __restrict__ x,
    unsigned short* __restrict__ Wbt, unsigned short* __restrict__ WslT,
    unsigned short* __restrict__ xb)
{
    const int blk = blockIdx.x, t = threadIdx.x;
    if (blk < 4) {
        const int n = blk * 256 + t;
        for (int k8 = 0; k8 < 256; k8 += 8) {
            unsigned short v[8];
#pragma unroll
            for (int j = 0; j < 8; j++) {
                float f = (n < 512) ? Wfx[(size_t)(k8 + j) * 512 + n]
                                    : Wx[(size_t)(k8 + j) * 512 + (n - 512)];
                v[j] = f2bf(f);
            }
            ushort4 u0 = {v[0], v[1], v[2], v[3]};
            ushort4 u1 = {v[4], v[5], v[6], v[7]};
            *(ushort4*)(Wbt + (size_t)n * 256 + k8) = u0;
            *(ushort4*)(Wbt + (size_t)n * 256 + k8 + 4) = u1;
        }
    } else if (blk == 4) {
        const int g = t >> 2, d0 = (t & 3) * 16;
        unsigned short v[16];
#pragma unroll
        for (int i = 0; i < 16; i++) v[i] = f2bf(Wsl[(size_t)(d0 + i) * 64 + g]);
#pragma unroll
        for (int q = 0; q < 4; q++) {
            ushort4 u = {v[q * 4], v[q * 4 + 1], v[q * 4 + 2], v[q * 4 + 3]};
            *(ushort4*)(WslT + (size_t)g * 64 + d0 + q * 4) = u;
        }
    } else {
        // x [4*32768][256] fp32 -> bf16, grid-stride, 8 elems/thread/iter
        const size_t TOT = (size_t)MTOT * 256;
        size_t i = ((size_t)(blk - 5) * 256 + t) * 8;
        const size_t stride = (size_t)(gridDim.x - 5) * 256 * 8;
        for (; i < TOT; i += stride) {
            float4 f0 = *(const float4*)(x + i);
            float4 f1 = *(const float4*)(x + i + 4);
            u32x4 v;
            v.x = pkbf(f0.x, f0.y); v.y = pkbf(f0.z, f0.w);
            v.z = pkbf(f1.x, f1.y); v.w = pkbf(f1.z, f1.w);
            *(u32x4*)(xb + i) = v;
        }
    }
}

// ---------------------------------------------------------------------------
// K1: mega-fused per-head kernel (1-D grid 2048, XCD-affinity swizzle).
// R10-exact (proven 353us): 51KB LDS, (256,3), compile-time gather indices.
// ---------------------------------------------------------------------------
__global__ __launch_bounds__(256, 3) void k_projfused(
    const unsigned short* __restrict__ xb,     // [M][256] bf16
    const unsigned short* __restrict__ Wbt,    // [1024][256] bf16
    const float* __restrict__ bfx, const float* __restrict__ bx,
    const unsigned short* __restrict__ WslTg,  // [64 g][64 d] bf16
    const float* __restrict__ bsl, const float* __restrict__ temp,
    unsigned short* __restrict__ wN,           // [8 h][M][64 g] bf16 planes
    float* __restrict__ tp,                    // [b][h][64 cb][64 g][64 d] partials
    float* __restrict__ np)                    // [b][h][64 cb][4 w][64 g] partials
{
    __shared__ unsigned short S[128 * 64 * 2];   // A[128][64] + B[128][64]; fxS overlay
    __shared__ unsigned short X[128 * PADD];     // xm; wsmT overlay

    // XCD-affinity decode: blocks L with L%8==xcd serve chunks [xcd*32, xcd*32+32)
    const int L = blockIdx.x;
    const int xcd = L & 7;
    const int j = L >> 3;                  // 0..255
    const int chunk = xcd * 32 + (j >> 3); // 0..255
    const int h = j & 7;

    const int b = chunk >> 6;              // 64 chunks per batch
    const int t = threadIdx.x;
    const int w = t >> 6, lane = t & 63;
    const int wm = w >> 1, wn = w & 1;
    const int l15 = lane & 15, quad = lane >> 4;

    unsigned short* A  = S;                // [128][64]
    unsigned short* Bs = S + 128 * 64;     // [128][64]
    unsigned short* fxS = S;               // [64][PADN] overlay
    unsigned short* wsmT = X;              // [64][PADN] overlay

    bf16x8 wslf[4][2];
#pragma unroll
    for (int c = 0; c < 4; c++)
#pragma unroll
        for (int ks = 0; ks < 2; ks++)
            wslf[c][ks] = *(const bf16x8*)&WslTg[(c * 16 + l15) * 64 + ks * 32 + quad * 8];

    float tv = temp[h];
    tv = fminf(fmaxf(tv, 0.1f), 5.0f);
    const float itemp = 1.0f / tv;
    float bsl_c[4], bfx_c[4], bx_c[4];
#pragma unroll
    for (int c = 0; c < 4; c++) {
        bsl_c[c] = bsl[c * 16 + l15];
        bfx_c[c] = bfx[h * 64 + c * 16 + l15];
        bx_c[c]  = bx[h * 64 + c * 16 + l15];
    }

    f32x4 pacc[4];
#pragma unroll
    for (int c = 0; c < 4; c++) pacc[c] = (f32x4){0.f, 0.f, 0.f, 0.f};
    float ns[4] = {0.f, 0.f, 0.f, 0.f};

    unsigned short* plane = wN + (size_t)h * MTOT * 64;

    for (int mt = 0; mt < 4; mt++) {
        const int n_in_b = ((chunk & 63) * 4 + mt) * 128;
        const size_t m0 = (size_t)b * NPTS + n_in_b;

        f32x4 acc[4][4];
#pragma unroll
        for (int r = 0; r < 4; r++)
#pragma unroll
            for (int c = 0; c < 4; c++) acc[r][c] = (f32x4){0.f, 0.f, 0.f, 0.f};

        for (int kb = 0; kb < 256; kb += 64) {
            __syncthreads();
#pragma unroll
            for (int rr = 0; rr < 4; rr++) {
                int flat = rr * 256 + t;
                int row = flat >> 3, colg = (flat & 7) * 8;
                gll16(xb + (m0 + row) * 256 + kb + colg, (char*)A + flat * 16);
                int grow = (rr < 2) ? (h * 64 + row) : (512 + h * 64 + (row - 64));
                gll16(Wbt + (size_t)grow * 256 + kb + colg, (char*)Bs + flat * 16);
            }
            __syncthreads();
#pragma unroll
            for (int ks = 0; ks < 2; ks++) {
                bf16x8 af[4], bfv[4];
#pragma unroll
                for (int r = 0; r < 4; r++)
                    af[r] = *(const bf16x8*)&A[(wm * 64 + r * 16 + l15) * 64 + ks * 32 + quad * 8];
#pragma unroll
                for (int c = 0; c < 4; c++)
                    bfv[c] = *(const bf16x8*)&Bs[(wn * 64 + c * 16 + l15) * 64 + ks * 32 + quad * 8];
#pragma unroll
                for (int r = 0; r < 4; r++)
#pragma unroll
                    for (int c = 0; c < 4; c++)
                        acc[r][c] = __builtin_amdgcn_mfma_f32_16x16x32_bf16(af[r], bfv[c], acc[r][c], 0, 0, 0);
            }
        }

        // ---- epilogue: fx -> fxS (wn==0 waves), x_mid -> xm (wn==1 waves) ----
        __syncthreads();
        if (wn == 0) {
#pragma unroll
            for (int r = 0; r < 4; r++)
#pragma unroll
                for (int c = 0; c < 4; c++) {
                    ushort4 u;
                    u.x = f2bf(acc[r][c][0] + bfx_c[c]);
                    u.y = f2bf(acc[r][c][1] + bfx_c[c]);
                    u.z = f2bf(acc[r][c][2] + bfx_c[c]);
                    u.w = f2bf(acc[r][c][3] + bfx_c[c]);
                    *(ushort4*)&fxS[(c * 16 + l15) * PADN + wm * 64 + r * 16 + quad * 4] = u;
                }
        } else {
#pragma unroll
            for (int r = 0; r < 4; r++)
#pragma unroll
                for (int c = 0; c < 4; c++)
#pragma unroll
                    for (int j2 = 0; j2 < 4; j2++)
                        X[(wm * 64 + r * 16 + quad * 4 + j2) * PADD + c * 16 + l15] =
                            f2bf(acc[r][c][j2] + bx_c[c]);
        }
        __syncthreads();

        // ---- logits MFMA ----
        f32x4 lacc[2][4];
#pragma unroll
        for (int rt = 0; rt < 2; rt++)
#pragma unroll
            for (int c = 0; c < 4; c++)
                lacc[rt][c] = (f32x4){bsl_c[c], bsl_c[c], bsl_c[c], bsl_c[c]};
#pragma unroll
        for (int ks = 0; ks < 2; ks++) {
            bf16x8 laf[2];
#pragma unroll
            for (int rt = 0; rt < 2; rt++)
                laf[rt] = *(const bf16x8*)&X[(w * 32 + rt * 16 + l15) * PADD + ks * 32 + quad * 8];
#pragma unroll
            for (int rt = 0; rt < 2; rt++)
#pragma unroll
                for (int c = 0; c < 4; c++)
                    lacc[rt][c] = __builtin_amdgcn_mfma_f32_16x16x32_bf16(laf[rt], wslf[c][ks], lacc[rt][c], 0, 0, 0);
        }
        __syncthreads();   // xm dead -> wsmT overlays X

        // ---- softmax -> wsmT[g][n]; ns ----
#pragma unroll
        for (int rt = 0; rt < 2; rt++) {
            float wv[4][4];
#pragma unroll
            for (int j2 = 0; j2 < 4; j2++) {
                float v0 = lacc[rt][0][j2] * itemp;
                float v1 = lacc[rt][1][j2] * itemp;
                float v2 = lacc[rt][2][j2] * itemp;
                float v3 = lacc[rt][3][j2] * itemp;
                float mx = fmaxf(fmaxf(v0, v1), fmaxf(v2, v3));
                mx = fmaxf(mx, __shfl_xor(mx, 1));
                mx = fmaxf(mx, __shfl_xor(mx, 2));
                mx = fmaxf(mx, __shfl_xor(mx, 4));
                mx = fmaxf(mx, __shfl_xor(mx, 8));
                float e0 = __expf(v0 - mx), e1 = __expf(v1 - mx);
                float e2 = __expf(v2 - mx), e3 = __expf(v3 - mx);
                float s = e0 + e1 + e2 + e3;
                s += __shfl_xor(s, 1);
                s += __shfl_xor(s, 2);
                s += __shfl_xor(s, 4);
                s += __shfl_xor(s, 8);
                float inv = 1.0f / s;
                wv[0][j2] = e0 * inv; wv[1][j2] = e1 * inv;
                wv[2][j2] = e2 * inv; wv[3][j2] = e3 * inv;
                ns[0] += wv[0][j2]; ns[1] += wv[1][j2];
                ns[2] += wv[2][j2]; ns[3] += wv[3][j2];
            }
#pragma unroll
            for (int c = 0; c < 4; c++) {
                ushort4 u;
                u.x = f2bf(wv[c][0]); u.y = f2bf(wv[c][1]);
                u.z = f2bf(wv[c][2]); u.w = f2bf(wv[c][3]);
                *(ushort4*)&wsmT[(c * 16 + l15) * PADN + w * 32 + rt * 16 + quad * 4] = u;
            }
        }
        __syncthreads();

        // ---- pooling MFMA ----
#pragma unroll
        for (int kk = 0; kk < 4; kk++) {
            bf16x8 paf = *(const bf16x8*)&wsmT[(w * 16 + l15) * PADN + kk * 32 + quad * 8];
#pragma unroll
            for (int c = 0; c < 4; c++) {
                bf16x8 pbf = *(const bf16x8*)&fxS[(c * 16 + l15) * PADN + kk * 32 + quad * 8];
                pacc[c] = __builtin_amdgcn_mfma_f32_16x16x32_bf16(paf, pbf, pacc[c], 0, 0, 0);
            }
        }

        // ---- wN write: per-head plane [M][64]; a wave stores 8 consecutive
        //      rows x 128 B = 1 KB fully contiguous per instruction ----
        {
            const int rsub = t >> 3;          // 0..31
            const int c16 = (t & 7) * 8;      // 16-B g-chunk
#pragma unroll
            for (int rr = 0; rr < 4; rr++) {
                const int n = rr * 32 + rsub;
                __attribute__((aligned(16))) unsigned short tmp[8];
#pragma unroll
                for (int i = 0; i < 8; i++)
                    tmp[i] = wsmT[(c16 + i) * PADN + n];
                *(u32x4*)(plane + (m0 + n) * 64 + c16) = *(const u32x4*)tmp;
            }
        }
    }

    // ---- block-end partial writes (plain stores, no atomics) ----
    const size_t cb = (size_t)(b * 8 + h) * 64 + (chunk & 63);
    float* tpb = tp + cb * 4096;
#pragma unroll
    for (int c = 0; c < 4; c++)
#pragma unroll
        for (int j2 = 0; j2 < 4; j2++)
            tpb[(size_t)(w * 16 + quad * 4 + j2) * 64 + c * 16 + l15] = pacc[c][j2];
#pragma unroll
    for (int c = 0; c < 4; c++) {
        ns[c] += __shfl_xor(ns[c], 16);
        ns[c] += __shfl_xor(ns[c], 32);
    }
    if (quad == 0) {
        float* npb = np + (cb * 4 + w) * 64;
#pragma unroll
        for (int c = 0; c < 4; c++)
            npb[c * 16 + l15] = ns[c];
    }
}

// ---------------------------------------------------------------------------
// K2: reduce per-chunk partials -> token_num [bh][64][64], norm [bh][64].
// ---------------------------------------------------------------------------
__global__ __launch_bounds__(256) void k_red(
    const float* __restrict__ tp, const float* __restrict__ np,
    float* __restrict__ token_num, float* __restrict__ norm)
{
    const int bh = blockIdx.x >> 4, seg = blockIdx.x & 15;
    const int t = threadIdx.x;
    float s = 0.f;
    const float* base = tp + (size_t)bh * 64 * 4096 + seg * 256 + t;
    for (int c = 0; c < 64; c++) s += base[(size_t)c * 4096];
    token_num[(size_t)bh * 4096 + seg * 256 + t] = s;
    if (seg == 0 && t < 64) {
        float nsum = 0.f;
        const float* nb = np + (size_t)bh * 64 * 4 * 64 + t;
        for (int i = 0; i < 256; i++) nsum += nb[(size_t)i * 64];
        norm[bh * 64 + t] = nsum;
    }
}

// ---------------------------------------------------------------------------
// K3+K5 fused (R14): per-(b,h) block does attention over 64 slice tokens,
// keeps out_slice in LDS (overlay on dead tok), then computes
// Mt[c][hg] = sum_d os[g][d] * W_out[h*64+d][c] directly. Saves one launch
// + the 512 KB os global round-trip. Phase-B osl reads are wave-uniform
// (broadcast, conflict-free).
// ---------------------------------------------------------------------------
__global__ __launch_bounds__(256) void k_attnm(
    const float* __restrict__ token_num, const float* __restrict__ norm,
    const float* __restrict__ Wq, const float* __restrict__ Wk,
    const float* __restrict__ Wv, const float* __restrict__ W_out,
    unsigned short* __restrict__ Mt_hi, unsigned short* __restrict__ Mt_lo)
{
    const int bh = blockIdx.x;
    const int t = threadIdx.x;
    const int gg = t >> 2, qq = t & 3;

    __shared__ float tok[64][68];   // overlaid by osl after phase A's first loop
    __shared__ float qS[64][68];
    __shared__ float kS[64][68];
    __shared__ float vS[64][68];
    __shared__ float pS[64][68];
    __shared__ float Wqs[64][64], Wks[64][64], Wvs[64][64];
    float* osl = &tok[0][0];        // [64][68] overlay

    for (int i = t; i < 4096; i += 256) {
        int g = i >> 6, dd = i & 63;
        Wqs[g][dd] = Wq[i];
        Wks[g][dd] = Wk[i];
        Wvs[g][dd] = Wv[i];
        tok[g][dd] = token_num[(size_t)bh * 4096 + i] / (norm[bh * 64 + g] + 1e-5f);
    }
    __syncthreads();

    float aq[16] = {}, ak[16] = {}, av[16] = {};
    for (int k = 0; k < 64; k++) {
        const float tv = tok[gg][k];
        const float4* wq4 = (const float4*)&Wqs[k][qq * 16];
        const float4* wk4 = (const float4*)&Wks[k][qq * 16];
        const float4* wv4 = (const float4*)&Wvs[k][qq * 16];
#pragma unroll
        for (int j4 = 0; j4 < 4; j4++) {
            float4 a = wq4[j4], bq = wk4[j4], c = wv4[j4];
            aq[j4*4+0] = fmaf(tv, a.x,  aq[j4*4+0]);
            aq[j4*4+1] = fmaf(tv, a.y,  aq[j4*4+1]);
            aq[j4*4+2] = fmaf(tv, a.z,  aq[j4*4+2]);
            aq[j4*4+3] = fmaf(tv, a.w,  aq[j4*4+3]);
            ak[j4*4+0] = fmaf(tv, bq.x, ak[j4*4+0]);
            ak[j4*4+1] = fmaf(tv, bq.y, ak[j4*4+1]);
            ak[j4*4+2] = fmaf(tv, bq.z, ak[j4*4+2]);
            ak[j4*4+3] = fmaf(tv, bq.w, ak[j4*4+3]);
            av[j4*4+0] = fmaf(tv, c.x,  av[j4*4+0]);
            av[j4*4+1] = fmaf(tv, c.y,  av[j4*4+1]);
            av[j4*4+2] = fmaf(tv, c.z,  av[j4*4+2]);
            av[j4*4+3] = fmaf(tv, c.w,  av[j4*4+3]);
        }
    }
#pragma unroll
    for (int j = 0; j < 16; j++) {
        qS[gg][qq * 16 + j] = aq[j];
        kS[gg][qq * 16 + j] = ak[j];
        vS[gg][qq * 16 + j] = av[j];
    }
    __syncthreads();

    float sc[16] = {};
    for (int d4 = 0; d4 < 16; d4++) {
        float4 q4 = *(const float4*)&qS[gg][d4 * 4];
#pragma unroll
        for (int j = 0; j < 16; j++) {
            float4 k4 = *(const float4*)&kS[qq * 16 + j][d4 * 4];
            sc[j] = fmaf(q4.x, k4.x, sc[j]);
            sc[j] = fmaf(q4.y, k4.y, sc[j]);
            sc[j] = fmaf(q4.z, k4.z, sc[j]);
            sc[j] = fmaf(q4.w, k4.w, sc[j]);
        }
    }
    const float SCALE = 0.125f;
    float mx = -1e30f;
#pragma unroll
    for (int j = 0; j < 16; j++) { sc[j] *= SCALE; mx = fmaxf(mx, sc[j]); }
    mx = fmaxf(mx, __shfl_xor(mx, 1));
    mx = fmaxf(mx, __shfl_xor(mx, 2));
    float s = 0.f;
#pragma unroll
    for (int j = 0; j < 16; j++) { sc[j] = __expf(sc[j] - mx); s += sc[j]; }
    s += __shfl_xor(s, 1);
    s += __shfl_xor(s, 2);
    const float invs = 1.0f / s;
#pragma unroll
    for (int j = 0; j < 16; j++) pS[gg][qq * 16 + j] = sc[j] * invs;
    __syncthreads();

    float oo[16] = {};
    for (int j = 0; j < 64; j++) {
        const float pv = pS[gg][j];
        const float4* v4p = (const float4*)&vS[j][qq * 16];
#pragma unroll
        for (int d4 = 0; d4 < 4; d4++) {
            float4 v4 = v4p[d4];
            oo[d4*4+0] = fmaf(pv, v4.x, oo[d4*4+0]);
            oo[d4*4+1] = fmaf(pv, v4.y, oo[d4*4+1]);
            oo[d4*4+2] = fmaf(pv, v4.z, oo[d4*4+2]);
            oo[d4*4+3] = fmaf(pv, v4.w, oo[d4*4+3]);
        }
    }
    __syncthreads();   // tok fully dead -> osl overlay safe
#pragma unroll
    for (int j = 0; j < 16; j++)
        osl[gg * 68 + qq * 16 + j] = oo[j];
    __syncthreads();

    // ---- phase B (k_m): Mt[c][h*64+g] = sum_d osl[g][d] * W_out[h*64+d][c]
    const int h = bh & 7, b = bh >> 3;
    float acc[64];
#pragma unroll
    for (int g = 0; g < 64; g++) acc[g] = 0.f;
    for (int d = 0; d < 64; d++) {
        float wv = W_out[(size_t)(h * 64 + d) * 256 + t];
#pragma unroll
        for (int g = 0; g < 64; g++) acc[g] = fmaf(osl[g * 68 + d], wv, acc[g]);
    }
    unsigned short* ph = Mt_hi + (size_t)(b * 256 + t) * 512 + h * 64;
    unsigned short* pl = Mt_lo + (size_t)(b * 256 + t) * 512 + h * 64;
#pragma unroll
    for (int g4 = 0; g4 < 16; g4++) {
        ushort4 uh, ul;
        unsigned short hh; float v, lo;
        v = acc[g4*4+0]; hh = f2bf(v); lo = v - bf2f(hh); uh.x = hh; ul.x = f2bf(lo);
        v = acc[g4*4+1]; hh = f2bf(v); lo = v - bf2f(hh); uh.y = hh; ul.y = f2bf(lo);
        v = acc[g4*4+2]; hh = f2bf(v); lo = v - bf2f(hh); uh.z = hh; ul.z = f2bf(lo);
        v = acc[g4*4+3]; hh = f2bf(v); lo = v - bf2f(hh); uh.w = hh; ul.w = f2bf(lo);
        *(ushort4*)(ph + g4 * 4) = uh;
        *(ushort4*)(pl + g4 * 4) = ul;
    }
}

// ---------------------------------------------------------------------------
// K6: out = wN @ (Mt_hi+Mt_lo)^T + bout.  R10-exact restore (best measured):
// LDS-staged A/Bh/Bl, 128x128 tile, (256,3), XCD-affinity swizzle. The
// R11 full-N/8-wave variant measured neutral (+13us) -> reverted.
// ---------------------------------------------------------------------------
__global__ __launch_bounds__(256, 3) void k_out(
    const unsigned short* __restrict__ wN,
    const unsigned short* __restrict__ Mt_hi, const unsigned short* __restrict__ Mt_lo,
    const float* __restrict__ bout, float* __restrict__ out)
{
    __shared__ unsigned short A[128 * 64];
    __shared__ unsigned short Bh[128 * 64];
    __shared__ unsigned short Bl[128 * 64];
    const int L = blockIdx.x;              // 0..2047
    const int xcd = L & 7;
    const int j = L >> 3;                  // 0..255
    const int mtile = xcd * 128 + (j >> 1);
    const int ntile = j & 1;
    const int m0 = mtile * 128, col0 = ntile * 128;
    const int b = m0 >> 15;
    const int t = threadIdx.x;
    const int w = t >> 6, lane = t & 63, l15 = lane & 15, quad = lane >> 4;
    const int wm = w >> 1, wn = w & 1;

    f32x4 acc[4][4];
#pragma unroll
    for (int r = 0; r < 4; r++)
#pragma unroll
        for (int c = 0; c < 4; c++) acc[r][c] = (f32x4){0.f, 0.f, 0.f, 0.f};

    for (int kb = 0; kb < 512; kb += 64) {
        const unsigned short* planeA = wN + (size_t)(kb >> 6) * MTOT * 64;
        __syncthreads();
#pragma unroll
        for (int rr = 0; rr < 4; rr++) {
            int flat = rr * 256 + t;
            int row = flat >> 3, col = (flat & 7) * 8;
            gll16(planeA + (size_t)(m0 + row) * 64 + col, (char*)A + flat * 16);
            gll16(Mt_hi + (size_t)(b * 256 + col0 + row) * 512 + kb + col, (char*)Bh + flat * 16);
            gll16(Mt_lo + (size_t)(b * 256 + col0 + row) * 512 + kb + col, (char*)Bl + flat * 16);
        }
        __syncthreads();
#pragma unroll
        for (int ks = 0; ks < 2; ks++) {
            bf16x8 af[4], bh4[4], bl4[4];
#pragma unroll
            for (int r = 0; r < 4; r++)
                af[r] = *(const bf16x8*)&A[(wm * 64 + r * 16 + l15) * 64 + ks * 32 + quad * 8];
#pragma unroll
            for (int c = 0; c < 4; c++) {
                bh4[c] = *(const bf16x8*)&Bh[(wn * 64 + c * 16 + l15) * 64 + ks * 32 + quad * 8];
                bl4[c] = *(const bf16x8*)&Bl[(wn * 64 + c * 16 + l15) * 64 + ks * 32 + quad * 8];
            }
#pragma unroll
            for (int r = 0; r < 4; r++)
#pragma unroll
                for (int c = 0; c < 4; c++) {
                    acc[r][c] = __builtin_amdgcn_mfma_f32_16x16x32_bf16(af[r], bh4[c], acc[r][c], 0, 0, 0);
                    acc[r][c] = __builtin_amdgcn_mfma_f32_16x16x32_bf16(af[r], bl4[c], acc[r][c], 0, 0, 0);
                }
        }
    }
    float biasc[4];
#pragma unroll
    for (int c = 0; c < 4; c++) biasc[c] = bout[col0 + wn * 64 + c * 16 + l15];
#pragma unroll
    for (int r = 0; r < 4; r++)
#pragma unroll
        for (int c = 0; c < 4; c++)
#pragma unroll
            for (int j2 = 0; j2 < 4; j2++)
                out[(size_t)(m0 + wm * 64 + r * 16 + quad * 4 + j2) * 256 + col0 + wn * 64 + c * 16 + l15] =
                    acc[r][c][j2] + biasc[c];
}

// ---------------------------------------------------------------------------
extern "C" void kernel_launch(void* const* d_in, const int* in_sizes, int n_in,
                              void* d_out, int out_size, void* d_ws, size_t ws_size,
                              hipStream_t stream) {
    const float* x    = (const float*)d_in[0];
    const float* Wfx  = (const float*)d_in[1];
    const float* bfx  = (const float*)d_in[2];
    const float* Wx   = (const float*)d_in[3];
    const float* bx   = (const float*)d_in[4];
    const float* Wsl  = (const float*)d_in[5];
    const float* bsl  = (const float*)d_in[6];
    const float* temp = (const float*)d_in[7];
    const float* Wq   = (const float*)d_in[8];
    const float* Wk   = (const float*)d_in[9];
    const float* Wv   = (const float*)d_in[10];
    const float* Wout = (const float*)d_in[11];
    const float* bout = (const float*)d_in[12];
    float* out = (float*)d_out;

    const int Mtotal = in_sizes[0] / DIM;   // 131072
    const int B = Mtotal / NPTS;            // 4

    // workspace (~138 MB peak)
    char* p = (char*)d_ws;
    unsigned short* Wbt   = (unsigned short*)p; p += (size_t)1024 * 256 * 2;        // 512 KB
    unsigned short* WslTg = (unsigned short*)p; p += (size_t)64 * 64 * 2;           // 8 KB
    unsigned short* wN    = (unsigned short*)p; p += (size_t)Mtotal * INNER * 2;    // 134 MB
    float* token_num = (float*)p; p += (size_t)B * 8 * 64 * 64 * 4;                 // 512 KB
    float* norm_ws   = (float*)p; p += (size_t)B * 8 * 64 * 4;                      // 8 KB
    unsigned short* Mt_hi = (unsigned short*)p; p += (size_t)B * 256 * 512 * 2;     // 1 MB
    unsigned short* Mt_lo = (unsigned short*)p; p += (size_t)B * 256 * 512 * 2;     // 1 MB

    // d_out (128 MB) double-duty: [0,64MB) xb bf16 x; [64MB,...) partial sums.
    // k_red consumes partials before k_out overwrites out.
    unsigned short* xb = (unsigned short*)d_out;
    float* tp = (float*)((char*)d_out + (size_t)Mtotal * DIM * 2);                  // 33.5 MB
    float* np = tp + (size_t)B * 8 * 64 * 4096;                                     // 2 MB

    k_prep<<<2048, 256, 0, stream>>>(Wfx, Wx, Wsl, x, Wbt, WslTg, xb);
    k_projfused<<<2048, 256, 0, stream>>>(
        xb, Wbt, bfx, bx, WslTg, bsl, temp, wN, tp, np);
    k_red<<<B * 8 * 16, 256, 0, stream>>>(tp, np, token_num, norm_ws);
    k_attnm<<<B * 8, 256, 0, stream>>>(token_num, norm_ws, Wq, Wk, Wv, Wout, Mt_hi, Mt_lo);
    k_out<<<2048, 256, 0, stream>>>(wN, Mt_hi, Mt_lo, bout, out);
}